// Round 19
// baseline (225.628 us; speedup 1.0000x reference)
//
#include <hip/hip_runtime.h>
#include <math.h>

typedef _Float16 f16;
typedef _Float16 f16x8 __attribute__((ext_vector_type(8)));
typedef _Float16 f16x4 __attribute__((ext_vector_type(4)));
typedef float    f32x4 __attribute__((ext_vector_type(4)));

#define MFMA16(A,B,C) __builtin_amdgcn_mfma_f32_16x16x32_f16(A,B,C,0,0,0)

#define QS   40            // qkv row stride in halfs (80 B: 16B-aligned, 8-bank spread)
#define HSZ  (32*QS)       // one 32-row head region (2560 B)
#define OFFK (6*HSZ)
#define OFFV (12*HSZ)
#define OFFO (18*HSZ)      // branch-1 O bank (survives to deferred proj)
#define XS   200           // x-tile row stride in halfs (400 B: 8-bank spread)
#define XOFF (24*HSZ)      // x-tile offset within half
#define HALF_TOTAL (24*HSZ + 32*XS)   // 37120 halfs = 74240 B per batch element

// f16 weight cache offsets (in halfs) inside d_ws.
#define W_QKV   0
#define W_QKVC  110592
#define W_PROJ  221184
#define W_PROJC 258048
#define W_DWT   294912     // depthwise weights transposed [tap][576]
#define W_RPB   300096     // rpbX[h][n][m] f16 (6*32*32)
#define W_TOTAL 306240

__global__ void cvt_weights(const float* __restrict__ a, const float* __restrict__ b,
                            const float* __restrict__ c, const float* __restrict__ d,
                            const float* __restrict__ dw, const float* __restrict__ rpb,
                            f16* __restrict__ ws)
{
    int i = blockIdx.x * 256 + threadIdx.x;   // chunk id; 19848 chunks
    if (i < 13824) {
        // qkv + qkvC: chunk i -> (h, kt, mt, lane); row (mt>>1)*192 + 32h + (mt&1)*16
        int h = i / 2304, r = i % 2304;
        int kt = r / 384, r2 = r % 384;
        int mt = r2 / 64, lane = r2 & 63;
        int l15 = lane & 15, g = lane >> 4;
        int row = (mt >> 1)*192 + h*32 + (mt & 1)*16 + l15;
        int src = row*192 + kt*32 + 8*g;
        f16* qa = ws + W_QKV  + i*8;
        f16* qb = ws + W_QKVC + i*8;
        #pragma unroll
        for (int e = 0; e < 8; ++e) {
            qa[e] = (f16)a[src + e];
            qb[e] = (f16)b[src + e];
        }
    } else if (i < 13824 + 4608) {
        // proj + projC: chunk j -> (h, kt, ct, lane); row 32h + 16ct
        int j = i - 13824;
        int h = j / 768, r = j % 768;
        int kt = r / 128, r2 = r % 128;
        int ct = r2 / 64, lane = r2 & 63;
        int l15 = lane & 15, g = lane >> 4;
        int src = (32*h + 16*ct + l15)*192 + kt*32 + 8*g;
        f16* qc = ws + W_PROJ  + j*8;
        f16* qd = ws + W_PROJC + j*8;
        #pragma unroll
        for (int e = 0; e < 8; ++e) {
            qc[e] = (f16)c[src + e];
            qd[e] = (f16)d[src + e];
        }
    } else if (i < 18432 + 648) {
        // depthwise transposed [tap][576]
        int j0 = (i - 18432) * 8;
        #pragma unroll
        for (int e = 0; e < 8; ++e) {
            int jj = j0 + e;
            int ch = jj % 576, tap = jj / 576;
            ws[W_DWT + jj] = (f16)dw[ch * 9 + tap];
        }
    } else if (i < 19080 + 768) {
        // rpbX[h][n][m] = rpb_table[relidx(m,n)][h]
        int j0 = (i - 19080) * 8;
        #pragma unroll
        for (int e = 0; e < 8; ++e) {
            int jj = j0 + e;            // h*1024 + n*32 + m
            int h = jj >> 10, r = jj & 1023;
            int n = r >> 5, m = r & 31;
            int dh = (m >> 3) - (n >> 3) + 3;
            int dwd = (m & 7) - (n & 7) + 7;
            ws[W_RPB + jj] = (f16)rpb[(dh*15 + dwd)*6 + h];
        }
    }
}

__device__ __forceinline__ f16x8 ldx8(const float* p)
{
    float4 u = *(const float4*)p;
    float4 v = *(const float4*)(p + 4);
    f16x8 r;
    r[0]=(f16)u.x; r[1]=(f16)u.y; r[2]=(f16)u.z; r[3]=(f16)u.w;
    r[4]=(f16)v.x; r[5]=(f16)v.y; r[6]=(f16)v.z; r[7]=(f16)v.w;
    return r;
}

// GEMM1 (this wave's head, all 6 mt-tiles): x from LDS; bias+scale; q/k row-major, v^T
template<bool W16>
__device__ __forceinline__ void g1_all(const f16* __restrict__ ws,
                                       const float* __restrict__ wf32,
                                       const f16* xh,
                                       const float* __restrict__ qkv_b,
                                       f16* sQh, f16* sKh, f16* sVh,
                                       int h, int lane, int l15, int g)
{
    const f32x4 z4 = {0.f, 0.f, 0.f, 0.f};
    f32x4 acc[6][2];
    #pragma unroll
    for (int i = 0; i < 6; ++i) { acc[i][0] = z4; acc[i][1] = z4; }
    #pragma unroll
    for (int kt = 0; kt < 6; ++kt) {
        f16x8 x0 = *(const f16x8*)(xh + l15*XS + kt*32 + g*8);
        f16x8 x1 = *(const f16x8*)(xh + (16 + l15)*XS + kt*32 + g*8);
        f16x8 af[6];
        #pragma unroll
        for (int i = 0; i < 6; ++i) {
            if constexpr (W16)
                af[i] = *(const f16x8*)(ws + (((h*6 + kt)*6 + i) << 9) + (lane << 3));
            else {
                int row = (i >> 1)*192 + h*32 + (i & 1)*16 + l15;
                af[i] = ldx8(wf32 + row*192 + kt*32 + g*8);
            }
        }
        #pragma unroll
        for (int i = 0; i < 6; ++i) {
            acc[i][0] = MFMA16(af[i], x0, acc[i][0]);
            acc[i][1] = MFMA16(af[i], x1, acc[i][1]);
        }
    }
    const float scale = 0.17677669529663687f;  // 32^-0.5
    #pragma unroll
    for (int i = 0; i < 6; ++i) {
        int which = i >> 1, sub = i & 1;
        int chb = which*192 + h*32 + sub*16;
        int db  = sub*16 + 4*g;
        float4 bi = *(const float4*)(qkv_b + chb + 4*g);
        #pragma unroll
        for (int nt = 0; nt < 2; ++nt) {
            int token = 16*nt + l15;
            f32x4 a = acc[i][nt];
            if (which == 0) {
                f16x4 o;
                o[0]=(f16)((a[0]+bi.x)*scale); o[1]=(f16)((a[1]+bi.y)*scale);
                o[2]=(f16)((a[2]+bi.z)*scale); o[3]=(f16)((a[3]+bi.w)*scale);
                *(f16x4*)(sQh + token*QS + db) = o;
            } else if (which == 1) {
                f16x4 o;
                o[0]=(f16)(a[0]+bi.x); o[1]=(f16)(a[1]+bi.y);
                o[2]=(f16)(a[2]+bi.z); o[3]=(f16)(a[3]+bi.w);
                *(f16x4*)(sKh + token*QS + db) = o;
            } else {   // V stored transposed: [d][token] for branch-1 PV
                sVh[(db+0)*QS + token] = (f16)(a[0]+bi.x);
                sVh[(db+1)*QS + token] = (f16)(a[1]+bi.y);
                sVh[(db+2)*QS + token] = (f16)(a[2]+bi.z);
                sVh[(db+3)*QS + token] = (f16)(a[3]+bi.w);
            }
        }
    }
}

// GEMM1C (all 6 mt-tiles): x from LDS; no bias; q/k ch-major, v token-major
template<bool W16>
__device__ __forceinline__ void g1c_all(const f16* __restrict__ ws,
                                        const float* __restrict__ wf32,
                                        const f16* xh,
                                        f16* sQh, f16* sKh, f16* sVh,
                                        int h, int lane, int l15, int g)
{
    const f32x4 z4 = {0.f, 0.f, 0.f, 0.f};
    f32x4 acc[6][2];
    #pragma unroll
    for (int i = 0; i < 6; ++i) { acc[i][0] = z4; acc[i][1] = z4; }
    #pragma unroll
    for (int kt = 0; kt < 6; ++kt) {
        f16x8 x0 = *(const f16x8*)(xh + l15*XS + kt*32 + g*8);
        f16x8 x1 = *(const f16x8*)(xh + (16 + l15)*XS + kt*32 + g*8);
        f16x8 af[6];
        #pragma unroll
        for (int i = 0; i < 6; ++i) {
            if constexpr (W16)
                af[i] = *(const f16x8*)(ws + (((h*6 + kt)*6 + i) << 9) + (lane << 3));
            else {
                int row = (i >> 1)*192 + h*32 + (i & 1)*16 + l15;
                af[i] = ldx8(wf32 + row*192 + kt*32 + g*8);
            }
        }
        #pragma unroll
        for (int i = 0; i < 6; ++i) {
            acc[i][0] = MFMA16(af[i], x0, acc[i][0]);
            acc[i][1] = MFMA16(af[i], x1, acc[i][1]);
        }
    }
    #pragma unroll
    for (int i = 0; i < 6; ++i) {
        int which = i >> 1, sub = i & 1;
        int db  = sub*16 + 4*g;
        f16* region = (which == 0) ? sQh : ((which == 1) ? sKh : sVh);
        #pragma unroll
        for (int nt = 0; nt < 2; ++nt) {
            int token = 16*nt + l15;
            f32x4 a = acc[i][nt];
            if (which == 2) {       // Yv token-major [n][dv] for vectorized conv
                f16x4 o;
                o[0]=(f16)a[0]; o[1]=(f16)a[1]; o[2]=(f16)a[2]; o[3]=(f16)a[3];
                *(f16x4*)(region + token*QS + db) = o;
            } else {                // Yq/Yk channel-major [d][n]
                region[(db+0)*QS + token] = (f16)a[0];
                region[(db+1)*QS + token] = (f16)a[1];
                region[(db+2)*QS + token] = (f16)a[2];
                region[(db+3)*QS + token] = (f16)a[3];
            }
        }
    }
}

template<bool W16>
__global__ __launch_bounds__(768, 3)
void vsa_kernel(const float* __restrict__ x,
                const float* __restrict__ qkv_w, const float* __restrict__ qkv_b,
                const float* __restrict__ proj_w, const float* __restrict__ proj_b,
                const float* __restrict__ rpb_table, const float* __restrict__ temperature,
                const float* __restrict__ qkvC_w, const float* __restrict__ dw_w,
                const float* __restrict__ projC_w, const float* __restrict__ projC_b,
                const float* __restrict__ gs_w1, const float* __restrict__ gs_b1,
                const float* __restrict__ bn_g, const float* __restrict__ bn_b,
                const float* __restrict__ bn_m, const float* __restrict__ bn_v,
                const float* __restrict__ gs_w2, const float* __restrict__ gs_b2,
                const f16* __restrict__ ws, float* __restrict__ out)
{
    // 12 waves = 2 batch elements x (wave == head); 3,3,3,3 SIMD placement.
    // R19: single 6-tile GEMM groups (6 loads in flight, 12 MFMA bursts;
    // halves LDS x re-reads); hoisted temperature/dlog chains.
    __shared__ __align__(16) f16 sQKV[2*HALF_TOTAL];
    __shared__ float aspl[32];

    const int t    = threadIdx.x;
    const int w12  = t >> 6;          // 0..11
    const int half = (w12 >= 6);      // batch sub-element
    const int h    = w12 - 6*half;    // wave == head, 0..5
    const int lane = t & 63;
    const int l15  = lane & 15;
    const int g    = lane >> 4;       // 0..3

    const float* xb = x + ((size_t)blockIdx.x*2 + half) * 6144;
    const f32x4 z4 = {0.f, 0.f, 0.f, 0.f};

    f16* base = sQKV + half*HALF_TOTAL;
    f16* sQh = base + h*HSZ;          // q -> P -> Yq -> P_c
    f16* sKh = base + OFFK + h*HSZ;   // k -> Yk -> O2
    f16* sVh = base + OFFV + h*HSZ;   // v^T -> Yv
    f16* sOh = base + OFFO + h*HSZ;   // O (branch-1 out), survives to proj
    f16* xh  = base + XOFF;           // f16 x tile [32][XS]

    // hoisted per-head scalars (long-latency chains overlap later work)
    const float temph = temperature[h];
    const float dlog  = logf(1.0f - exp2f(-2.0f - (2.0f*(float)h)/3.0f));

    // ---- spatial gate (one wave): batch-independent (pooled == 1/32 exactly) ----
    if (t < 32) {
        float y1 = gs_b1[t];
        #pragma unroll
        for (int hh = 0; hh < 6; ++hh) y1 += gs_w1[t*54 + hh*9 + 4] * (1.0f/32.0f);
        y1 = (y1 - bn_m[t]) * rsqrtf(bn_v[t] + 1e-5f) * bn_g[t] + bn_b[t];
        float y2 = gs_b2[t];
        #pragma unroll
        for (int c = 0; c < 32; ++c)
            y2 += gs_w2[t*288 + c*9 + 4] * __shfl(y1, c);
        aspl[t] = 1.0f + y2;
    }

    // ---- stage x as f16 into own half's LDS (coalesced, 2 chunks/thread) ----
    {
        int tl = t - half*384;        // 0..383
        #pragma unroll
        for (int it = 0; it < 2; ++it) {
            int c = tl + 384*it;      // 0..767 chunks of 8 halfs
            int row = c / 24, col = c % 24;
            f16x8 v = ldx8(xb + row*192 + col*8);
            *(f16x8*)(xh + row*XS + col*8) = v;
        }
    }
    __syncthreads();   // b0: x tiles staged

    // ========== GEMM1: this head's q,k,v (single 6-tile group) ==========
    g1_all<W16>(ws + W_QKV, qkv_w, xh, qkv_b, sQh, sKh, sVh, h, lane, l15, g);
    // no barrier: all wave-private

    // ========== branch-1 attention (wave-private) ==========
    {
        f16x8 qa[2], kb[2];
        #pragma unroll
        for (int mt = 0; mt < 2; ++mt)
            qa[mt] = *(const f16x8*)(sQh + (16*mt + l15)*QS + 8*g);
        #pragma unroll
        for (int nt = 0; nt < 2; ++nt)
            kb[nt] = *(const f16x8*)(sKh + (16*nt + l15)*QS + 8*g);
        f32x4 s[2][2];
        #pragma unroll
        for (int mt = 0; mt < 2; ++mt)
            #pragma unroll
            for (int nt = 0; nt < 2; ++nt)
                s[mt][nt] = MFMA16(qa[mt], kb[nt], z4);

        float pr[2][2][4];
        if constexpr (W16) {
            #pragma unroll
            for (int mt = 0; mt < 2; ++mt)
                #pragma unroll
                for (int nt = 0; nt < 2; ++nt) {
                    f16x4 rv = *(const f16x4*)(ws + W_RPB + h*1024
                               + (16*nt + l15)*32 + 16*mt + 4*g);
                    #pragma unroll
                    for (int r = 0; r < 4; ++r)
                        pr[mt][nt][r] = s[mt][nt][r] + (float)rv[r];
                }
        } else {
            #pragma unroll
            for (int mt = 0; mt < 2; ++mt)
                #pragma unroll
                for (int nt = 0; nt < 2; ++nt)
                    #pragma unroll
                    for (int r = 0; r < 4; ++r) {
                        int m = 16*mt + 4*g + r, n = 16*nt + l15;
                        int dh = (m>>3) - (n>>3) + 3;
                        int dwd = (m&7) - (n&7) + 7;
                        pr[mt][nt][r] = s[mt][nt][r] + rpb_table[(dh*15+dwd)*6 + h];
                    }
        }
        #pragma unroll
        for (int mt = 0; mt < 2; ++mt)
            #pragma unroll
            for (int r = 0; r < 4; ++r) {
                float mx = fmaxf(pr[mt][0][r], pr[mt][1][r]);
                mx = fmaxf(mx, __shfl_xor(mx, 1));
                mx = fmaxf(mx, __shfl_xor(mx, 2));
                mx = fmaxf(mx, __shfl_xor(mx, 4));
                mx = fmaxf(mx, __shfl_xor(mx, 8));
                float e0 = __expf(pr[mt][0][r] - mx);
                float e1 = __expf(pr[mt][1][r] - mx);
                float sm = e0 + e1;
                sm += __shfl_xor(sm, 1);
                sm += __shfl_xor(sm, 2);
                sm += __shfl_xor(sm, 4);
                sm += __shfl_xor(sm, 8);
                float inv = 1.0f / sm;
                pr[mt][0][r] = e0*inv;
                pr[mt][1][r] = e1*inv;
            }
        // P overwrites Q region (qa already in regs; wave-private)
        #pragma unroll
        for (int mt = 0; mt < 2; ++mt)
            #pragma unroll
            for (int nt = 0; nt < 2; ++nt)
                #pragma unroll
                for (int r = 0; r < 4; ++r)
                    sQh[(16*mt + 4*g + r)*QS + 16*nt + l15] = (f16)pr[mt][nt][r];

        // O^T = V^T @ P^T ; O -> O bank [token][d]
        f16x8 va[2], pb[2];
        #pragma unroll
        for (int mt = 0; mt < 2; ++mt)
            va[mt] = *(const f16x8*)(sVh + (16*mt + l15)*QS + 8*g);
        #pragma unroll
        for (int nt = 0; nt < 2; ++nt)
            pb[nt] = *(const f16x8*)(sQh + (16*nt + l15)*QS + 8*g);
        #pragma unroll
        for (int mt = 0; mt < 2; ++mt)
            #pragma unroll
            for (int nt = 0; nt < 2; ++nt) {
                f32x4 o = MFMA16(va[mt], pb[nt], z4);
                int token = 16*nt + l15;
                int dbv = 16*mt + 4*g;
                f16x4 ov;
                ov[0]=(f16)o[0]; ov[1]=(f16)o[1]; ov[2]=(f16)o[2]; ov[3]=(f16)o[3];
                *(f16x4*)(sOh + token*QS + dbv) = ov;
            }
    }

    // ========== GEMM1C: this head's Y (single 6-tile group), wave-private ==========
    g1c_all<W16>(ws + W_QKVC, qkvC_w, xh, sQh, sKh, sVh, h, lane, l15, g);

    // ========== branch-2 (MDTA), wave-private ==========
    {
        f16x8 qa[2], kb[2], vb[2];
        // q/k: depthwise 3x3 (3 vector row reads) + l2norm; coalesced f16 taps
        #pragma unroll
        for (int mt = 0; mt < 2; ++mt) {
            int d = 16*mt + l15;
            #pragma unroll
            for (int qk = 0; qk < 2; ++qk) {
                int ch = qk*192 + h*32 + d;
                float wr[9];
                if constexpr (W16) {
                    #pragma unroll
                    for (int i2 = 0; i2 < 9; ++i2)
                        wr[i2] = (float)ws[W_DWT + i2*576 + ch];
                } else {
                    const float* wp = dw_w + ch*9;
                    #pragma unroll
                    for (int i2 = 0; i2 < 9; ++i2) wr[i2] = wp[i2];
                }
                const f16* yr = (qk ? sKh : sQh) + d*QS;
                f16x8 row8[3];
                #pragma unroll
                for (int dh2 = 0; dh2 < 3; ++dh2) {
                    int h2 = g + dh2 - 1;
                    f16x8 rv;
                    if (h2 >= 0 && h2 < 4) rv = *(const f16x8*)(yr + 8*h2);
                    else { rv[0]=0;rv[1]=0;rv[2]=0;rv[3]=0;rv[4]=0;rv[5]=0;rv[6]=0;rv[7]=0; }
                    row8[dh2] = rv;
                }
                float z[8], ss = 0.f;
                #pragma unroll
                for (int b2 = 0; b2 < 8; ++b2) {
                    float s2 = 0.f;
                    #pragma unroll
                    for (int dh2 = 0; dh2 < 3; ++dh2)
                        #pragma unroll
                        for (int dw2 = 0; dw2 < 3; ++dw2) {
                            int w2 = b2 + dw2 - 1;
                            if (w2 >= 0 && w2 < 8)
                                s2 += wr[dh2*3+dw2] * (float)row8[dh2][w2];
                        }
                    z[b2] = s2; ss += s2*s2;
                }
                ss += __shfl_xor(ss, 16);
                ss += __shfl_xor(ss, 32);
                float inv = 1.0f / fmaxf(sqrtf(ss), 1e-12f);
                if (qk == 0) {
                    #pragma unroll
                    for (int b2 = 0; b2 < 8; ++b2) qa[mt][b2] = (f16)(z[b2]*inv);
                } else {
                    #pragma unroll
                    for (int b2 = 0; b2 < 8; ++b2) kb[mt][b2] = (f16)(z[b2]*inv);
                }
            }
        }
        // vc: depthwise on token-major Yv; tap-outer, w8 reused for both nt
        {
            float a8[2][8];
            #pragma unroll
            for (int nt = 0; nt < 2; ++nt)
                #pragma unroll
                for (int b2 = 0; b2 < 8; ++b2) a8[nt][b2] = 0.f;
            #pragma unroll
            for (int dh2 = 0; dh2 < 3; ++dh2)
                #pragma unroll
                for (int dw2 = 0; dw2 < 3; ++dw2) {
                    f16x8 w8;
                    if constexpr (W16) {
                        w8 = *(const f16x8*)(ws + W_DWT + (dh2*3+dw2)*576
                                             + 384 + h*32 + 8*g);
                    } else {
                        #pragma unroll
                        for (int b2 = 0; b2 < 8; ++b2)
                            w8[b2] = (f16)dw_w[(384+h*32+8*g+b2)*9 + dh2*3+dw2];
                    }
                    #pragma unroll
                    for (int nt = 0; nt < 2; ++nt) {
                        int n = 16*nt + l15;
                        int h2 = (n >> 3) + dh2 - 1;
                        int w2 = (n & 7) + dw2 - 1;
                        if (h2 >= 0 && h2 < 4 && w2 >= 0 && w2 < 8) {
                            f16x8 v8 = *(const f16x8*)(sVh + (h2*8+w2)*QS + 8*g);
                            #pragma unroll
                            for (int b2 = 0; b2 < 8; ++b2)
                                a8[nt][b2] += (float)w8[b2] * (float)v8[b2];
                        }
                    }
                }
            #pragma unroll
            for (int nt = 0; nt < 2; ++nt)
                #pragma unroll
                for (int b2 = 0; b2 < 8; ++b2) vb[nt][b2] = (f16)a8[nt][b2];
        }
        // S_c = qc kc^T * temp + |d-d'|*dlog ; softmax over d'
        f32x4 s[2][2];
        #pragma unroll
        for (int mt = 0; mt < 2; ++mt)
            #pragma unroll
            for (int nt = 0; nt < 2; ++nt)
                s[mt][nt] = MFMA16(qa[mt], kb[nt], z4);
        float pr[2][2][4];
        #pragma unroll
        for (int mt = 0; mt < 2; ++mt)
            #pragma unroll
            for (int nt = 0; nt < 2; ++nt)
                #pragma unroll
                for (int r = 0; r < 4; ++r) {
                    int di = 16*mt + 4*g + r, dj = 16*nt + l15;
                    pr[mt][nt][r] = s[mt][nt][r]*temph + fabsf((float)(di - dj))*dlog;
                }
        #pragma unroll
        for (int mt = 0; mt < 2; ++mt)
            #pragma unroll
            for (int r = 0; r < 4; ++r) {
                float mx = fmaxf(pr[mt][0][r], pr[mt][1][r]);
                mx = fmaxf(mx, __shfl_xor(mx, 1));
                mx = fmaxf(mx, __shfl_xor(mx, 2));
                mx = fmaxf(mx, __shfl_xor(mx, 4));
                mx = fmaxf(mx, __shfl_xor(mx, 8));
                float e0 = __expf(pr[mt][0][r] - mx);
                float e1 = __expf(pr[mt][1][r] - mx);
                float sm = e0 + e1;
                sm += __shfl_xor(sm, 1);
                sm += __shfl_xor(sm, 2);
                sm += __shfl_xor(sm, 4);
                sm += __shfl_xor(sm, 8);
                float inv = 1.0f / sm;
                pr[mt][0][r] = e0*inv;
                pr[mt][1][r] = e1*inv;
            }
        // P_c overwrites Yq region (consumed into qa; wave-private)
        #pragma unroll
        for (int mt = 0; mt < 2; ++mt)
            #pragma unroll
            for (int nt = 0; nt < 2; ++nt)
                #pragma unroll
                for (int r = 0; r < 4; ++r)
                    sQh[(16*mt + 4*g + r)*QS + 16*nt + l15] = (f16)pr[mt][nt][r];
        // x2pre[d][n] = P_c @ vc -> O2 into K region (Yk consumed into kb above)
        f16x8 pa[2];
        #pragma unroll
        for (int mt = 0; mt < 2; ++mt)
            pa[mt] = *(const f16x8*)(sQh + (16*mt + l15)*QS + 8*g);
        #pragma unroll
        for (int mt = 0; mt < 2; ++mt)
            #pragma unroll
            for (int nt = 0; nt < 2; ++nt) {
                f32x4 o = MFMA16(pa[mt], vb[nt], z4);
                int token = 16*nt + l15;
                int dbv = 16*mt + 4*g;
                f16x4 ov;
                ov[0]=(f16)o[0]; ov[1]=(f16)o[1]; ov[2]=(f16)o[2]; ov[3]=(f16)o[3];
                *(f16x4*)(sKh + token*QS + dbv) = ov;
            }
    }
    __syncthreads();   // b1: O (O banks) and O2 (K regions) ready across all heads

    // ========== deferred proj + projC (wave h -> cols 32h..32h+31, own half) =======
    f32x4 acc1[2][2], acc2[2][2];
    {
        #pragma unroll
        for (int ct = 0; ct < 2; ++ct) {
            float b1f = proj_b[32*h + 16*ct + l15];
            float b2f = projC_b[32*h + 16*ct + l15];
            f32x4 v1 = {b1f, b1f, b1f, b1f};
            f32x4 v2 = {b2f, b2f, b2f, b2f};
            acc1[0][ct] = v1; acc1[1][ct] = v1;
            acc2[0][ct] = v2; acc2[1][ct] = v2;
        }
        #pragma unroll
        for (int kt = 0; kt < 6; ++kt) {     // K-chunk kt == head kt
            f16x8 aa1[2], aa2[2], bb1[2], bb2[2];
            #pragma unroll
            for (int mt = 0; mt < 2; ++mt) {
                aa1[mt] = *(const f16x8*)(base + OFFO + kt*HSZ + (16*mt + l15)*QS + 8*g);
                aa2[mt] = *(const f16x8*)(base + OFFK + kt*HSZ + (16*mt + l15)*QS + 8*g);
            }
            #pragma unroll
            for (int ct = 0; ct < 2; ++ct) {
                if constexpr (W16) {
                    bb1[ct] = *(const f16x8*)(ws + W_PROJ
                              + (((h*6 + kt)*2 + ct) << 9) + (lane << 3));
                    bb2[ct] = *(const f16x8*)(ws + W_PROJC
                              + (((h*6 + kt)*2 + ct) << 9) + (lane << 3));
                } else {
                    bb1[ct] = ldx8(proj_w  + (32*h + 16*ct + l15)*192 + kt*32 + 8*g);
                    bb2[ct] = ldx8(projC_w + (32*h + 16*ct + l15)*192 + kt*32 + 8*g);
                }
            }
            #pragma unroll
            for (int mt = 0; mt < 2; ++mt)
                #pragma unroll
                for (int ct = 0; ct < 2; ++ct) {
                    acc1[mt][ct] = MFMA16(aa1[mt], bb1[ct], acc1[mt][ct]);
                    acc2[mt][ct] = MFMA16(aa2[mt], bb2[ct], acc2[mt][ct]);
                }
        }
    }
    __syncthreads();   // b2: all O/O2 reads done -> pool reusable as fp32 sOut

    // ========== epilogue: stage fp32 result in own LDS half, coalesced store =========
    float* sOut = (float*)base;
    #pragma unroll
    for (int mt = 0; mt < 2; ++mt)
        #pragma unroll
        for (int r = 0; r < 4; ++r) {
            int m = 16*mt + 4*g + r;
            float asp = aspl[m];
            #pragma unroll
            for (int ct = 0; ct < 2; ++ct) {
                int c = 32*h + 16*ct + l15;
                sOut[m*192 + c] = acc1[mt][ct][r] + acc2[mt][ct][r]*asp;
            }
        }
    __syncthreads();   // b3
    {
        int tl = t - half*384;   // 0..383 within half
        const float4* sOv = (const float4*)sOut;
        float4* ob4 = (float4*)(out + ((size_t)blockIdx.x*2 + half) * 6144);
        #pragma unroll
        for (int it = 0; it < 4; ++it)
            ob4[tl + 384*it] = sOv[tl + 384*it];
    }
}

extern "C" void kernel_launch(void* const* d_in, const int* in_sizes, int n_in,
                              void* d_out, int out_size, void* d_ws, size_t ws_size,
                              hipStream_t stream) {
    (void)n_in; (void)out_size;
    const float* x         = (const float*)d_in[0];
    const float* qkv_w     = (const float*)d_in[1];
    const float* qkv_b     = (const float*)d_in[2];
    const float* proj_w    = (const float*)d_in[3];
    const float* proj_b    = (const float*)d_in[4];
    const float* rpb_table = (const float*)d_in[5];
    const float* temp      = (const float*)d_in[6];
    const float* qkvC_w    = (const float*)d_in[7];
    const float* dw_w      = (const float*)d_in[8];
    const float* projC_w   = (const float*)d_in[9];
    const float* projC_b   = (const float*)d_in[10];
    const float* gs_w1     = (const float*)d_in[11];
    const float* gs_b1     = (const float*)d_in[12];
    const float* bn_g      = (const float*)d_in[13];
    const float* bn_b      = (const float*)d_in[14];
    const float* bn_m      = (const float*)d_in[15];
    const float* bn_v      = (const float*)d_in[16];
    const float* gs_w2     = (const float*)d_in[17];
    const float* gs_b2     = (const float*)d_in[18];
    float* out = (float*)d_out;

    int B = in_sizes[0] / (32 * 192);   // 4096
    bool use_ws = (d_ws != nullptr) && (ws_size >= (size_t)W_TOTAL * sizeof(f16));
    if (use_ws) {
        cvt_weights<<<78, 256, 0, stream>>>(qkv_w, qkvC_w, proj_w, projC_w, dw_w,
                                            rpb_table, (f16*)d_ws);
        vsa_kernel<true><<<B/2, 768, 0, stream>>>(x, qkv_w, qkv_b, proj_w, proj_b,
                                                  rpb_table, temp, qkvC_w, dw_w,
                                                  projC_w, projC_b, gs_w1, gs_b1,
                                                  bn_g, bn_b, bn_m, bn_v, gs_w2, gs_b2,
                                                  (const f16*)d_ws, out);
    } else {
        vsa_kernel<false><<<B/2, 768, 0, stream>>>(x, qkv_w, qkv_b, proj_w, proj_b,
                                                   rpb_table, temp, qkvC_w, dw_w,
                                                   projC_w, projC_b, gs_w1, gs_b1,
                                                   bn_g, bn_b, bn_m, bn_v, gs_w2, gs_b2,
                                                   nullptr, out);
    }
}

// Round 20
// 209.143 us; speedup vs baseline: 1.0788x; 1.0788x over previous
//
#include <hip/hip_runtime.h>
#include <math.h>

typedef _Float16 f16;
typedef _Float16 f16x8 __attribute__((ext_vector_type(8)));
typedef _Float16 f16x4 __attribute__((ext_vector_type(4)));
typedef float    f32x4 __attribute__((ext_vector_type(4)));

#define MFMA16(A,B,C) __builtin_amdgcn_mfma_f32_16x16x32_f16(A,B,C,0,0,0)

#define QS   40            // qkv row stride in halfs (80 B: 16B-aligned, 8-bank spread)
#define HSZ  (32*QS)       // one 32-row head region (2560 B)
#define OFFK (6*HSZ)
#define OFFV (12*HSZ)
#define OFFO (18*HSZ)      // branch-1 O bank (survives to deferred proj)
#define XS   200           // x-tile row stride in halfs (400 B: 8-bank spread)
#define XOFF (24*HSZ)      // x-tile offset within half
#define HALF_TOTAL (24*HSZ + 32*XS)   // 37120 halfs = 74240 B per batch element

// f16 weight cache offsets (in halfs) inside d_ws.
#define W_QKV   0
#define W_QKVC  110592
#define W_PROJ  221184
#define W_PROJC 258048
#define W_DWT   294912     // depthwise weights transposed [tap][576]
#define W_RPB   300096     // rpbX[h][n][m] f16 (6*32*32)
#define W_TOTAL 306240

__global__ void cvt_weights(const float* __restrict__ a, const float* __restrict__ b,
                            const float* __restrict__ c, const float* __restrict__ d,
                            const float* __restrict__ dw, const float* __restrict__ rpb,
                            f16* __restrict__ ws)
{
    int i = blockIdx.x * 256 + threadIdx.x;   // chunk id; 19848 chunks
    if (i < 13824) {
        // qkv + qkvC: chunk i -> (h, kt, mt, lane); row (mt>>1)*192 + 32h + (mt&1)*16
        int h = i / 2304, r = i % 2304;
        int kt = r / 384, r2 = r % 384;
        int mt = r2 / 64, lane = r2 & 63;
        int l15 = lane & 15, g = lane >> 4;
        int row = (mt >> 1)*192 + h*32 + (mt & 1)*16 + l15;
        int src = row*192 + kt*32 + 8*g;
        f16* qa = ws + W_QKV  + i*8;
        f16* qb = ws + W_QKVC + i*8;
        #pragma unroll
        for (int e = 0; e < 8; ++e) {
            qa[e] = (f16)a[src + e];
            qb[e] = (f16)b[src + e];
        }
    } else if (i < 13824 + 4608) {
        // proj + projC: chunk j -> (h, kt, ct, lane); row 32h + 16ct
        int j = i - 13824;
        int h = j / 768, r = j % 768;
        int kt = r / 128, r2 = r % 128;
        int ct = r2 / 64, lane = r2 & 63;
        int l15 = lane & 15, g = lane >> 4;
        int src = (32*h + 16*ct + l15)*192 + kt*32 + 8*g;
        f16* qc = ws + W_PROJ  + j*8;
        f16* qd = ws + W_PROJC + j*8;
        #pragma unroll
        for (int e = 0; e < 8; ++e) {
            qc[e] = (f16)c[src + e];
            qd[e] = (f16)d[src + e];
        }
    } else if (i < 18432 + 648) {
        // depthwise transposed [tap][576]
        int j0 = (i - 18432) * 8;
        #pragma unroll
        for (int e = 0; e < 8; ++e) {
            int jj = j0 + e;
            int ch = jj % 576, tap = jj / 576;
            ws[W_DWT + jj] = (f16)dw[ch * 9 + tap];
        }
    } else if (i < 19080 + 768) {
        // rpbX[h][n][m] = rpb_table[relidx(m,n)][h]
        int j0 = (i - 19080) * 8;
        #pragma unroll
        for (int e = 0; e < 8; ++e) {
            int jj = j0 + e;            // h*1024 + n*32 + m
            int h = jj >> 10, r = jj & 1023;
            int n = r >> 5, m = r & 31;
            int dh = (m >> 3) - (n >> 3) + 3;
            int dwd = (m & 7) - (n & 7) + 7;
            ws[W_RPB + jj] = (f16)rpb[(dh*15 + dwd)*6 + h];
        }
    }
}

__device__ __forceinline__ f16x8 ldx8(const float* p)
{
    float4 u = *(const float4*)p;
    float4 v = *(const float4*)(p + 4);
    f16x8 r;
    r[0]=(f16)u.x; r[1]=(f16)u.y; r[2]=(f16)u.z; r[3]=(f16)u.w;
    r[4]=(f16)v.x; r[5]=(f16)v.y; r[6]=(f16)v.z; r[7]=(f16)v.w;
    return r;
}

// GEMM1 (this wave's head, all 6 mt-tiles): x from LDS; bias+scale; q/k row-major, v^T
template<bool W16>
__device__ __forceinline__ void g1_all(const f16* __restrict__ ws,
                                       const float* __restrict__ wf32,
                                       const f16* xh,
                                       const float* __restrict__ qkv_b,
                                       f16* sQh, f16* sKh, f16* sVh,
                                       int h, int lane, int l15, int g)
{
    const f32x4 z4 = {0.f, 0.f, 0.f, 0.f};
    f32x4 acc[6][2];
    #pragma unroll
    for (int i = 0; i < 6; ++i) { acc[i][0] = z4; acc[i][1] = z4; }
    #pragma unroll
    for (int kt = 0; kt < 6; ++kt) {
        f16x8 x0 = *(const f16x8*)(xh + l15*XS + kt*32 + g*8);
        f16x8 x1 = *(const f16x8*)(xh + (16 + l15)*XS + kt*32 + g*8);
        f16x8 af[6];
        #pragma unroll
        for (int i = 0; i < 6; ++i) {
            if constexpr (W16)
                af[i] = *(const f16x8*)(ws + (((h*6 + kt)*6 + i) << 9) + (lane << 3));
            else {
                int row = (i >> 1)*192 + h*32 + (i & 1)*16 + l15;
                af[i] = ldx8(wf32 + row*192 + kt*32 + g*8);
            }
        }
        #pragma unroll
        for (int i = 0; i < 6; ++i) {
            acc[i][0] = MFMA16(af[i], x0, acc[i][0]);
            acc[i][1] = MFMA16(af[i], x1, acc[i][1]);
        }
    }
    const float scale = 0.17677669529663687f;  // 32^-0.5
    #pragma unroll
    for (int i = 0; i < 6; ++i) {
        int which = i >> 1, sub = i & 1;
        int chb = which*192 + h*32 + sub*16;
        int db  = sub*16 + 4*g;
        float4 bi = *(const float4*)(qkv_b + chb + 4*g);
        #pragma unroll
        for (int nt = 0; nt < 2; ++nt) {
            int token = 16*nt + l15;
            f32x4 a = acc[i][nt];
            if (which == 0) {
                f16x4 o;
                o[0]=(f16)((a[0]+bi.x)*scale); o[1]=(f16)((a[1]+bi.y)*scale);
                o[2]=(f16)((a[2]+bi.z)*scale); o[3]=(f16)((a[3]+bi.w)*scale);
                *(f16x4*)(sQh + token*QS + db) = o;
            } else if (which == 1) {
                f16x4 o;
                o[0]=(f16)(a[0]+bi.x); o[1]=(f16)(a[1]+bi.y);
                o[2]=(f16)(a[2]+bi.z); o[3]=(f16)(a[3]+bi.w);
                *(f16x4*)(sKh + token*QS + db) = o;
            } else {   // V stored transposed: [d][token] for branch-1 PV
                sVh[(db+0)*QS + token] = (f16)(a[0]+bi.x);
                sVh[(db+1)*QS + token] = (f16)(a[1]+bi.y);
                sVh[(db+2)*QS + token] = (f16)(a[2]+bi.z);
                sVh[(db+3)*QS + token] = (f16)(a[3]+bi.w);
            }
        }
    }
}

// GEMM1C (all 6 mt-tiles): x from LDS; no bias; q/k ch-major, v token-major
template<bool W16>
__device__ __forceinline__ void g1c_all(const f16* __restrict__ ws,
                                        const float* __restrict__ wf32,
                                        const f16* xh,
                                        f16* sQh, f16* sKh, f16* sVh,
                                        int h, int lane, int l15, int g)
{
    const f32x4 z4 = {0.f, 0.f, 0.f, 0.f};
    f32x4 acc[6][2];
    #pragma unroll
    for (int i = 0; i < 6; ++i) { acc[i][0] = z4; acc[i][1] = z4; }
    #pragma unroll
    for (int kt = 0; kt < 6; ++kt) {
        f16x8 x0 = *(const f16x8*)(xh + l15*XS + kt*32 + g*8);
        f16x8 x1 = *(const f16x8*)(xh + (16 + l15)*XS + kt*32 + g*8);
        f16x8 af[6];
        #pragma unroll
        for (int i = 0; i < 6; ++i) {
            if constexpr (W16)
                af[i] = *(const f16x8*)(ws + (((h*6 + kt)*6 + i) << 9) + (lane << 3));
            else {
                int row = (i >> 1)*192 + h*32 + (i & 1)*16 + l15;
                af[i] = ldx8(wf32 + row*192 + kt*32 + g*8);
            }
        }
        #pragma unroll
        for (int i = 0; i < 6; ++i) {
            acc[i][0] = MFMA16(af[i], x0, acc[i][0]);
            acc[i][1] = MFMA16(af[i], x1, acc[i][1]);
        }
    }
    #pragma unroll
    for (int i = 0; i < 6; ++i) {
        int which = i >> 1, sub = i & 1;
        int db  = sub*16 + 4*g;
        f16* region = (which == 0) ? sQh : ((which == 1) ? sKh : sVh);
        #pragma unroll
        for (int nt = 0; nt < 2; ++nt) {
            int token = 16*nt + l15;
            f32x4 a = acc[i][nt];
            if (which == 2) {       // Yv token-major [n][dv] for vectorized conv
                f16x4 o;
                o[0]=(f16)a[0]; o[1]=(f16)a[1]; o[2]=(f16)a[2]; o[3]=(f16)a[3];
                *(f16x4*)(region + token*QS + db) = o;
            } else {                // Yq/Yk channel-major [d][n]
                region[(db+0)*QS + token] = (f16)a[0];
                region[(db+1)*QS + token] = (f16)a[1];
                region[(db+2)*QS + token] = (f16)a[2];
                region[(db+3)*QS + token] = (f16)a[3];
            }
        }
    }
}

template<bool W16>
__global__ __launch_bounds__(768, 3)
void vsa_kernel(const float* __restrict__ x,
                const float* __restrict__ qkv_w, const float* __restrict__ qkv_b,
                const float* __restrict__ proj_w, const float* __restrict__ proj_b,
                const float* __restrict__ rpb_table, const float* __restrict__ temperature,
                const float* __restrict__ qkvC_w, const float* __restrict__ dw_w,
                const float* __restrict__ projC_w, const float* __restrict__ projC_b,
                const float* __restrict__ gs_w1, const float* __restrict__ gs_b1,
                const float* __restrict__ bn_g, const float* __restrict__ bn_b,
                const float* __restrict__ bn_m, const float* __restrict__ bn_v,
                const float* __restrict__ gs_w2, const float* __restrict__ gs_b2,
                const f16* __restrict__ ws, float* __restrict__ out)
{
    // 12 waves = 2 batch elements x (wave == head); 3,3,3,3 SIMD placement.
    // R20: packed-f16 depthwise convolutions (v_pk_fma_f16, no per-element cvt).
    __shared__ __align__(16) f16 sQKV[2*HALF_TOTAL];
    __shared__ float aspl[32];

    const int t    = threadIdx.x;
    const int w12  = t >> 6;          // 0..11
    const int half = (w12 >= 6);      // batch sub-element
    const int h    = w12 - 6*half;    // wave == head, 0..5
    const int lane = t & 63;
    const int l15  = lane & 15;
    const int g    = lane >> 4;       // 0..3

    const float* xb = x + ((size_t)blockIdx.x*2 + half) * 6144;
    const f32x4 z4 = {0.f, 0.f, 0.f, 0.f};

    f16* base = sQKV + half*HALF_TOTAL;
    f16* sQh = base + h*HSZ;          // q -> P -> Yq -> P_c
    f16* sKh = base + OFFK + h*HSZ;   // k -> Yk -> O2
    f16* sVh = base + OFFV + h*HSZ;   // v^T -> Yv
    f16* sOh = base + OFFO + h*HSZ;   // O (branch-1 out), survives to proj
    f16* xh  = base + XOFF;           // f16 x tile [32][XS]

    // hoisted per-head scalars (long-latency chains overlap later work)
    const float temph = temperature[h];
    const float dlog  = logf(1.0f - exp2f(-2.0f - (2.0f*(float)h)/3.0f));

    // ---- spatial gate (one wave): batch-independent (pooled == 1/32 exactly) ----
    if (t < 32) {
        float y1 = gs_b1[t];
        #pragma unroll
        for (int hh = 0; hh < 6; ++hh) y1 += gs_w1[t*54 + hh*9 + 4] * (1.0f/32.0f);
        y1 = (y1 - bn_m[t]) * rsqrtf(bn_v[t] + 1e-5f) * bn_g[t] + bn_b[t];
        float y2 = gs_b2[t];
        #pragma unroll
        for (int c = 0; c < 32; ++c)
            y2 += gs_w2[t*288 + c*9 + 4] * __shfl(y1, c);
        aspl[t] = 1.0f + y2;
    }

    // ---- stage x as f16 into own half's LDS (coalesced, 2 chunks/thread) ----
    {
        int tl = t - half*384;        // 0..383
        #pragma unroll
        for (int it = 0; it < 2; ++it) {
            int c = tl + 384*it;      // 0..767 chunks of 8 halfs
            int row = c / 24, col = c % 24;
            f16x8 v = ldx8(xb + row*192 + col*8);
            *(f16x8*)(xh + row*XS + col*8) = v;
        }
    }
    __syncthreads();   // b0: x tiles staged

    // ========== GEMM1: this head's q,k,v (single 6-tile group) ==========
    g1_all<W16>(ws + W_QKV, qkv_w, xh, qkv_b, sQh, sKh, sVh, h, lane, l15, g);
    // no barrier: all wave-private

    // ========== branch-1 attention (wave-private) ==========
    {
        f16x8 qa[2], kb[2];
        #pragma unroll
        for (int mt = 0; mt < 2; ++mt)
            qa[mt] = *(const f16x8*)(sQh + (16*mt + l15)*QS + 8*g);
        #pragma unroll
        for (int nt = 0; nt < 2; ++nt)
            kb[nt] = *(const f16x8*)(sKh + (16*nt + l15)*QS + 8*g);
        f32x4 s[2][2];
        #pragma unroll
        for (int mt = 0; mt < 2; ++mt)
            #pragma unroll
            for (int nt = 0; nt < 2; ++nt)
                s[mt][nt] = MFMA16(qa[mt], kb[nt], z4);

        float pr[2][2][4];
        if constexpr (W16) {
            #pragma unroll
            for (int mt = 0; mt < 2; ++mt)
                #pragma unroll
                for (int nt = 0; nt < 2; ++nt) {
                    f16x4 rv = *(const f16x4*)(ws + W_RPB + h*1024
                               + (16*nt + l15)*32 + 16*mt + 4*g);
                    #pragma unroll
                    for (int r = 0; r < 4; ++r)
                        pr[mt][nt][r] = s[mt][nt][r] + (float)rv[r];
                }
        } else {
            #pragma unroll
            for (int mt = 0; mt < 2; ++mt)
                #pragma unroll
                for (int nt = 0; nt < 2; ++nt)
                    #pragma unroll
                    for (int r = 0; r < 4; ++r) {
                        int m = 16*mt + 4*g + r, n = 16*nt + l15;
                        int dh = (m>>3) - (n>>3) + 3;
                        int dwd = (m&7) - (n&7) + 7;
                        pr[mt][nt][r] = s[mt][nt][r] + rpb_table[(dh*15+dwd)*6 + h];
                    }
        }
        #pragma unroll
        for (int mt = 0; mt < 2; ++mt)
            #pragma unroll
            for (int r = 0; r < 4; ++r) {
                float mx = fmaxf(pr[mt][0][r], pr[mt][1][r]);
                mx = fmaxf(mx, __shfl_xor(mx, 1));
                mx = fmaxf(mx, __shfl_xor(mx, 2));
                mx = fmaxf(mx, __shfl_xor(mx, 4));
                mx = fmaxf(mx, __shfl_xor(mx, 8));
                float e0 = __expf(pr[mt][0][r] - mx);
                float e1 = __expf(pr[mt][1][r] - mx);
                float sm = e0 + e1;
                sm += __shfl_xor(sm, 1);
                sm += __shfl_xor(sm, 2);
                sm += __shfl_xor(sm, 4);
                sm += __shfl_xor(sm, 8);
                float inv = 1.0f / sm;
                pr[mt][0][r] = e0*inv;
                pr[mt][1][r] = e1*inv;
            }
        // P overwrites Q region (qa already in regs; wave-private)
        #pragma unroll
        for (int mt = 0; mt < 2; ++mt)
            #pragma unroll
            for (int nt = 0; nt < 2; ++nt)
                #pragma unroll
                for (int r = 0; r < 4; ++r)
                    sQh[(16*mt + 4*g + r)*QS + 16*nt + l15] = (f16)pr[mt][nt][r];

        // O^T = V^T @ P^T ; O -> O bank [token][d]
        f16x8 va[2], pb[2];
        #pragma unroll
        for (int mt = 0; mt < 2; ++mt)
            va[mt] = *(const f16x8*)(sVh + (16*mt + l15)*QS + 8*g);
        #pragma unroll
        for (int nt = 0; nt < 2; ++nt)
            pb[nt] = *(const f16x8*)(sQh + (16*nt + l15)*QS + 8*g);
        #pragma unroll
        for (int mt = 0; mt < 2; ++mt)
            #pragma unroll
            for (int nt = 0; nt < 2; ++nt) {
                f32x4 o = MFMA16(va[mt], pb[nt], z4);
                int token = 16*nt + l15;
                int dbv = 16*mt + 4*g;
                f16x4 ov;
                ov[0]=(f16)o[0]; ov[1]=(f16)o[1]; ov[2]=(f16)o[2]; ov[3]=(f16)o[3];
                *(f16x4*)(sOh + token*QS + dbv) = ov;
            }
    }

    // ========== GEMM1C: this head's Y (single 6-tile group), wave-private ==========
    g1c_all<W16>(ws + W_QKVC, qkvC_w, xh, sQh, sKh, sVh, h, lane, l15, g);

    // ========== branch-2 (MDTA), wave-private; packed-f16 convolutions ==========
    {
        const f16x8 zz = {0,0,0,0,0,0,0,0};
        f16x8 qa[2], kb[2], vb[2];
        // q/k: depthwise 3x3 via f16x8 vector FMA (+ shifted shuffles) + f32 l2norm
        #pragma unroll
        for (int mt = 0; mt < 2; ++mt) {
            int d = 16*mt + l15;
            #pragma unroll
            for (int qk = 0; qk < 2; ++qk) {
                int ch = qk*192 + h*32 + d;
                f16 wr[9];
                if constexpr (W16) {
                    #pragma unroll
                    for (int i2 = 0; i2 < 9; ++i2)
                        wr[i2] = ws[W_DWT + i2*576 + ch];
                } else {
                    const float* wp = dw_w + ch*9;
                    #pragma unroll
                    for (int i2 = 0; i2 < 9; ++i2) wr[i2] = (f16)wp[i2];
                }
                const f16* yr = (qk ? sKh : sQh) + d*QS;
                f16x8 zv = zz;
                #pragma unroll
                for (int dh2 = 0; dh2 < 3; ++dh2) {
                    int h2 = g + dh2 - 1;
                    if (h2 >= 0 && h2 < 4) {
                        f16x8 rv = *(const f16x8*)(yr + 8*h2);
                        f16x8 sm1 = __builtin_shufflevector(rv, zz, 8,0,1,2,3,4,5,6);
                        f16x8 sp1 = __builtin_shufflevector(rv, zz, 1,2,3,4,5,6,7,8);
                        zv += sm1 * wr[dh2*3+0];
                        zv += rv  * wr[dh2*3+1];
                        zv += sp1 * wr[dh2*3+2];
                    }
                }
                float ss = 0.f;
                #pragma unroll
                for (int b2 = 0; b2 < 8; ++b2) {
                    float zf = (float)zv[b2];
                    ss += zf*zf;
                }
                ss += __shfl_xor(ss, 16);
                ss += __shfl_xor(ss, 32);
                float inv = 1.0f / fmaxf(sqrtf(ss), 1e-12f);
                f16 invh = (f16)inv;
                if (qk == 0) qa[mt] = zv * invh;
                else         kb[mt] = zv * invh;
            }
        }
        // vc: depthwise on token-major Yv; tap-outer, packed f16 accumulate
        {
            f16x8 av0 = zz, av1 = zz;
            #pragma unroll
            for (int dh2 = 0; dh2 < 3; ++dh2)
                #pragma unroll
                for (int dw2 = 0; dw2 < 3; ++dw2) {
                    f16x8 w8;
                    if constexpr (W16) {
                        w8 = *(const f16x8*)(ws + W_DWT + (dh2*3+dw2)*576
                                             + 384 + h*32 + 8*g);
                    } else {
                        #pragma unroll
                        for (int b2 = 0; b2 < 8; ++b2)
                            w8[b2] = (f16)dw_w[(384+h*32+8*g+b2)*9 + dh2*3+dw2];
                    }
                    {   // nt = 0
                        int n = l15;
                        int h2 = (n >> 3) + dh2 - 1;
                        int w2 = (n & 7) + dw2 - 1;
                        if (h2 >= 0 && h2 < 4 && w2 >= 0 && w2 < 8) {
                            f16x8 v8 = *(const f16x8*)(sVh + (h2*8+w2)*QS + 8*g);
                            av0 += w8 * v8;
                        }
                    }
                    {   // nt = 1
                        int n = 16 + l15;
                        int h2 = (n >> 3) + dh2 - 1;
                        int w2 = (n & 7) + dw2 - 1;
                        if (h2 >= 0 && h2 < 4 && w2 >= 0 && w2 < 8) {
                            f16x8 v8 = *(const f16x8*)(sVh + (h2*8+w2)*QS + 8*g);
                            av1 += w8 * v8;
                        }
                    }
                }
            vb[0] = av0; vb[1] = av1;
        }
        // S_c = qc kc^T * temp + |d-d'|*dlog ; softmax over d'
        f32x4 s[2][2];
        #pragma unroll
        for (int mt = 0; mt < 2; ++mt)
            #pragma unroll
            for (int nt = 0; nt < 2; ++nt)
                s[mt][nt] = MFMA16(qa[mt], kb[nt], z4);
        float pr[2][2][4];
        #pragma unroll
        for (int mt = 0; mt < 2; ++mt)
            #pragma unroll
            for (int nt = 0; nt < 2; ++nt)
                #pragma unroll
                for (int r = 0; r < 4; ++r) {
                    int di = 16*mt + 4*g + r, dj = 16*nt + l15;
                    pr[mt][nt][r] = s[mt][nt][r]*temph + fabsf((float)(di - dj))*dlog;
                }
        #pragma unroll
        for (int mt = 0; mt < 2; ++mt)
            #pragma unroll
            for (int r = 0; r < 4; ++r) {
                float mx = fmaxf(pr[mt][0][r], pr[mt][1][r]);
                mx = fmaxf(mx, __shfl_xor(mx, 1));
                mx = fmaxf(mx, __shfl_xor(mx, 2));
                mx = fmaxf(mx, __shfl_xor(mx, 4));
                mx = fmaxf(mx, __shfl_xor(mx, 8));
                float e0 = __expf(pr[mt][0][r] - mx);
                float e1 = __expf(pr[mt][1][r] - mx);
                float sm = e0 + e1;
                sm += __shfl_xor(sm, 1);
                sm += __shfl_xor(sm, 2);
                sm += __shfl_xor(sm, 4);
                sm += __shfl_xor(sm, 8);
                float inv = 1.0f / sm;
                pr[mt][0][r] = e0*inv;
                pr[mt][1][r] = e1*inv;
            }
        // P_c overwrites Yq region (consumed into qa; wave-private)
        #pragma unroll
        for (int mt = 0; mt < 2; ++mt)
            #pragma unroll
            for (int nt = 0; nt < 2; ++nt)
                #pragma unroll
                for (int r = 0; r < 4; ++r)
                    sQh[(16*mt + 4*g + r)*QS + 16*nt + l15] = (f16)pr[mt][nt][r];
        // x2pre[d][n] = P_c @ vc -> O2 into K region (Yk consumed into kb above)
        f16x8 pa[2];
        #pragma unroll
        for (int mt = 0; mt < 2; ++mt)
            pa[mt] = *(const f16x8*)(sQh + (16*mt + l15)*QS + 8*g);
        #pragma unroll
        for (int mt = 0; mt < 2; ++mt)
            #pragma unroll
            for (int nt = 0; nt < 2; ++nt) {
                f32x4 o = MFMA16(pa[mt], vb[nt], z4);
                int token = 16*nt + l15;
                int dbv = 16*mt + 4*g;
                f16x4 ov;
                ov[0]=(f16)o[0]; ov[1]=(f16)o[1]; ov[2]=(f16)o[2]; ov[3]=(f16)o[3];
                *(f16x4*)(sKh + token*QS + dbv) = ov;
            }
    }
    __syncthreads();   // b1: O (O banks) and O2 (K regions) ready across all heads

    // ========== deferred proj + projC (wave h -> cols 32h..32h+31, own half) =======
    f32x4 acc1[2][2], acc2[2][2];
    {
        #pragma unroll
        for (int ct = 0; ct < 2; ++ct) {
            float b1f = proj_b[32*h + 16*ct + l15];
            float b2f = projC_b[32*h + 16*ct + l15];
            f32x4 v1 = {b1f, b1f, b1f, b1f};
            f32x4 v2 = {b2f, b2f, b2f, b2f};
            acc1[0][ct] = v1; acc1[1][ct] = v1;
            acc2[0][ct] = v2; acc2[1][ct] = v2;
        }
        #pragma unroll
        for (int kt = 0; kt < 6; ++kt) {     // K-chunk kt == head kt
            f16x8 aa1[2], aa2[2], bb1[2], bb2[2];
            #pragma unroll
            for (int mt = 0; mt < 2; ++mt) {
                aa1[mt] = *(const f16x8*)(base + OFFO + kt*HSZ + (16*mt + l15)*QS + 8*g);
                aa2[mt] = *(const f16x8*)(base + OFFK + kt*HSZ + (16*mt + l15)*QS + 8*g);
            }
            #pragma unroll
            for (int ct = 0; ct < 2; ++ct) {
                if constexpr (W16) {
                    bb1[ct] = *(const f16x8*)(ws + W_PROJ
                              + (((h*6 + kt)*2 + ct) << 9) + (lane << 3));
                    bb2[ct] = *(const f16x8*)(ws + W_PROJC
                              + (((h*6 + kt)*2 + ct) << 9) + (lane << 3));
                } else {
                    bb1[ct] = ldx8(proj_w  + (32*h + 16*ct + l15)*192 + kt*32 + 8*g);
                    bb2[ct] = ldx8(projC_w + (32*h + 16*ct + l15)*192 + kt*32 + 8*g);
                }
            }
            #pragma unroll
            for (int mt = 0; mt < 2; ++mt)
                #pragma unroll
                for (int ct = 0; ct < 2; ++ct) {
                    acc1[mt][ct] = MFMA16(aa1[mt], bb1[ct], acc1[mt][ct]);
                    acc2[mt][ct] = MFMA16(aa2[mt], bb2[ct], acc2[mt][ct]);
                }
        }
    }
    __syncthreads();   // b2: all O/O2 reads done -> pool reusable as fp32 sOut

    // ========== epilogue: stage fp32 result in own LDS half, coalesced store =========
    float* sOut = (float*)base;
    #pragma unroll
    for (int mt = 0; mt < 2; ++mt)
        #pragma unroll
        for (int r = 0; r < 4; ++r) {
            int m = 16*mt + 4*g + r;
            float asp = aspl[m];
            #pragma unroll
            for (int ct = 0; ct < 2; ++ct) {
                int c = 32*h + 16*ct + l15;
                sOut[m*192 + c] = acc1[mt][ct][r] + acc2[mt][ct][r]*asp;
            }
        }
    __syncthreads();   // b3
    {
        int tl = t - half*384;   // 0..383 within half
        const float4* sOv = (const float4*)sOut;
        float4* ob4 = (float4*)(out + ((size_t)blockIdx.x*2 + half) * 6144);
        #pragma unroll
        for (int it = 0; it < 4; ++it)
            ob4[tl + 384*it] = sOv[tl + 384*it];
    }
}

extern "C" void kernel_launch(void* const* d_in, const int* in_sizes, int n_in,
                              void* d_out, int out_size, void* d_ws, size_t ws_size,
                              hipStream_t stream) {
    (void)n_in; (void)out_size;
    const float* x         = (const float*)d_in[0];
    const float* qkv_w     = (const float*)d_in[1];
    const float* qkv_b     = (const float*)d_in[2];
    const float* proj_w    = (const float*)d_in[3];
    const float* proj_b    = (const float*)d_in[4];
    const float* rpb_table = (const float*)d_in[5];
    const float* temp      = (const float*)d_in[6];
    const float* qkvC_w    = (const float*)d_in[7];
    const float* dw_w      = (const float*)d_in[8];
    const float* projC_w   = (const float*)d_in[9];
    const float* projC_b   = (const float*)d_in[10];
    const float* gs_w1     = (const float*)d_in[11];
    const float* gs_b1     = (const float*)d_in[12];
    const float* bn_g      = (const float*)d_in[13];
    const float* bn_b      = (const float*)d_in[14];
    const float* bn_m      = (const float*)d_in[15];
    const float* bn_v      = (const float*)d_in[16];
    const float* gs_w2     = (const float*)d_in[17];
    const float* gs_b2     = (const float*)d_in[18];
    float* out = (float*)d_out;

    int B = in_sizes[0] / (32 * 192);   // 4096
    bool use_ws = (d_ws != nullptr) && (ws_size >= (size_t)W_TOTAL * sizeof(f16));
    if (use_ws) {
        cvt_weights<<<78, 256, 0, stream>>>(qkv_w, qkvC_w, proj_w, projC_w, dw_w,
                                            rpb_table, (f16*)d_ws);
        vsa_kernel<true><<<B/2, 768, 0, stream>>>(x, qkv_w, qkv_b, proj_w, proj_b,
                                                  rpb_table, temp, qkvC_w, dw_w,
                                                  projC_w, projC_b, gs_w1, gs_b1,
                                                  bn_g, bn_b, bn_m, bn_v, gs_w2, gs_b2,
                                                  (const f16*)d_ws, out);
    } else {
        vsa_kernel<false><<<B/2, 768, 0, stream>>>(x, qkv_w, qkv_b, proj_w, proj_b,
                                                   rpb_table, temp, qkvC_w, dw_w,
                                                   projC_w, projC_b, gs_w1, gs_b1,
                                                   bn_g, bn_b, bn_m, bn_v, gs_w2, gs_b2,
                                                   nullptr, out);
    }
}

// Round 21
// 196.174 us; speedup vs baseline: 1.1501x; 1.0661x over previous
//
#include <hip/hip_runtime.h>
#include <math.h>

typedef _Float16 f16;
typedef _Float16 f16x8 __attribute__((ext_vector_type(8)));
typedef _Float16 f16x4 __attribute__((ext_vector_type(4)));
typedef float    f32x4 __attribute__((ext_vector_type(4)));

#define MFMA16(A,B,C) __builtin_amdgcn_mfma_f32_16x16x32_f16(A,B,C,0,0,0)

#define QS   40            // qkv row stride in halfs (80 B: 16B-aligned, 8-bank spread)
#define HSZ  (32*QS)       // one 32-row head region (2560 B)
#define OFFK (6*HSZ)
#define OFFV (12*HSZ)
#define OFFO (18*HSZ)      // branch-1 O bank (survives to deferred proj)
#define XS   200           // x-tile row stride in halfs (400 B: 8-bank spread)
#define XOFF (24*HSZ)      // x-tile offset within half
#define HALF_TOTAL (24*HSZ + 32*XS)   // 37120 halfs = 74240 B per batch element

// f16 weight cache offsets (in halfs) inside d_ws.
#define W_QKV   0
#define W_QKVC  110592
#define W_PROJ  221184
#define W_PROJC 258048
#define W_DWT   294912     // depthwise weights transposed [tap][576]
#define W_RPB   300096     // rpbX[h][n][m] f16 (6*32*32)
#define W_TOTAL 306240

__global__ void cvt_weights(const float* __restrict__ a, const float* __restrict__ b,
                            const float* __restrict__ c, const float* __restrict__ d,
                            const float* __restrict__ dw, const float* __restrict__ rpb,
                            f16* __restrict__ ws)
{
    int i = blockIdx.x * 256 + threadIdx.x;   // chunk id; 19848 chunks
    if (i < 13824) {
        // qkv + qkvC: chunk i -> (h, kt, mt, lane); row (mt>>1)*192 + 32h + (mt&1)*16
        int h = i / 2304, r = i % 2304;
        int kt = r / 384, r2 = r % 384;
        int mt = r2 / 64, lane = r2 & 63;
        int l15 = lane & 15, g = lane >> 4;
        int row = (mt >> 1)*192 + h*32 + (mt & 1)*16 + l15;
        int src = row*192 + kt*32 + 8*g;
        f16* qa = ws + W_QKV  + i*8;
        f16* qb = ws + W_QKVC + i*8;
        #pragma unroll
        for (int e = 0; e < 8; ++e) {
            qa[e] = (f16)a[src + e];
            qb[e] = (f16)b[src + e];
        }
    } else if (i < 13824 + 4608) {
        // proj + projC: chunk j -> (h, kt, ct, lane); row 32h + 16ct
        int j = i - 13824;
        int h = j / 768, r = j % 768;
        int kt = r / 128, r2 = r % 128;
        int ct = r2 / 64, lane = r2 & 63;
        int l15 = lane & 15, g = lane >> 4;
        int src = (32*h + 16*ct + l15)*192 + kt*32 + 8*g;
        f16* qc = ws + W_PROJ  + j*8;
        f16* qd = ws + W_PROJC + j*8;
        #pragma unroll
        for (int e = 0; e < 8; ++e) {
            qc[e] = (f16)c[src + e];
            qd[e] = (f16)d[src + e];
        }
    } else if (i < 18432 + 648) {
        // depthwise transposed [tap][576]
        int j0 = (i - 18432) * 8;
        #pragma unroll
        for (int e = 0; e < 8; ++e) {
            int jj = j0 + e;
            int ch = jj % 576, tap = jj / 576;
            ws[W_DWT + jj] = (f16)dw[ch * 9 + tap];
        }
    } else if (i < 19080 + 768) {
        // rpbX[h][n][m] = rpb_table[relidx(m,n)][h]
        int j0 = (i - 19080) * 8;
        #pragma unroll
        for (int e = 0; e < 8; ++e) {
            int jj = j0 + e;            // h*1024 + n*32 + m
            int h = jj >> 10, r = jj & 1023;
            int n = r >> 5, m = r & 31;
            int dh = (m >> 3) - (n >> 3) + 3;
            int dwd = (m & 7) - (n & 7) + 7;
            ws[W_RPB + jj] = (f16)rpb[(dh*15 + dwd)*6 + h];
        }
    }
}

__device__ __forceinline__ f16x8 ldx8(const float* p)
{
    float4 u = *(const float4*)p;
    float4 v = *(const float4*)(p + 4);
    f16x8 r;
    r[0]=(f16)u.x; r[1]=(f16)u.y; r[2]=(f16)u.z; r[3]=(f16)u.w;
    r[4]=(f16)v.x; r[5]=(f16)v.y; r[6]=(f16)v.z; r[7]=(f16)v.w;
    return r;
}

// GEMM1 (this wave's head, all 6 mt-tiles): x from LDS; bias+scale; q/k row-major, v^T
template<bool W16>
__device__ __forceinline__ void g1_all(const f16* __restrict__ ws,
                                       const float* __restrict__ wf32,
                                       const f16* xh,
                                       const float* __restrict__ qkv_b,
                                       f16* sQh, f16* sKh, f16* sVh,
                                       int h, int lane, int l15, int g)
{
    const f32x4 z4 = {0.f, 0.f, 0.f, 0.f};
    f32x4 acc[6][2];
    #pragma unroll
    for (int i = 0; i < 6; ++i) { acc[i][0] = z4; acc[i][1] = z4; }
    #pragma unroll
    for (int kt = 0; kt < 6; ++kt) {
        f16x8 x0 = *(const f16x8*)(xh + l15*XS + kt*32 + g*8);
        f16x8 x1 = *(const f16x8*)(xh + (16 + l15)*XS + kt*32 + g*8);
        f16x8 af[6];
        #pragma unroll
        for (int i = 0; i < 6; ++i) {
            if constexpr (W16)
                af[i] = *(const f16x8*)(ws + (((h*6 + kt)*6 + i) << 9) + (lane << 3));
            else {
                int row = (i >> 1)*192 + h*32 + (i & 1)*16 + l15;
                af[i] = ldx8(wf32 + row*192 + kt*32 + g*8);
            }
        }
        #pragma unroll
        for (int i = 0; i < 6; ++i) {
            acc[i][0] = MFMA16(af[i], x0, acc[i][0]);
            acc[i][1] = MFMA16(af[i], x1, acc[i][1]);
        }
    }
    const float scale = 0.17677669529663687f;  // 32^-0.5
    #pragma unroll
    for (int i = 0; i < 6; ++i) {
        int which = i >> 1, sub = i & 1;
        int chb = which*192 + h*32 + sub*16;
        int db  = sub*16 + 4*g;
        float4 bi = *(const float4*)(qkv_b + chb + 4*g);
        #pragma unroll
        for (int nt = 0; nt < 2; ++nt) {
            int token = 16*nt + l15;
            f32x4 a = acc[i][nt];
            if (which == 0) {
                f16x4 o;
                o[0]=(f16)((a[0]+bi.x)*scale); o[1]=(f16)((a[1]+bi.y)*scale);
                o[2]=(f16)((a[2]+bi.z)*scale); o[3]=(f16)((a[3]+bi.w)*scale);
                *(f16x4*)(sQh + token*QS + db) = o;
            } else if (which == 1) {
                f16x4 o;
                o[0]=(f16)(a[0]+bi.x); o[1]=(f16)(a[1]+bi.y);
                o[2]=(f16)(a[2]+bi.z); o[3]=(f16)(a[3]+bi.w);
                *(f16x4*)(sKh + token*QS + db) = o;
            } else {   // V stored transposed: [d][token] for branch-1 PV
                sVh[(db+0)*QS + token] = (f16)(a[0]+bi.x);
                sVh[(db+1)*QS + token] = (f16)(a[1]+bi.y);
                sVh[(db+2)*QS + token] = (f16)(a[2]+bi.z);
                sVh[(db+3)*QS + token] = (f16)(a[3]+bi.w);
            }
        }
    }
}

// GEMM1C (all 6 mt-tiles): x from LDS; no bias; q/k ch-major, v token-major
template<bool W16>
__device__ __forceinline__ void g1c_all(const f16* __restrict__ ws,
                                        const float* __restrict__ wf32,
                                        const f16* xh,
                                        f16* sQh, f16* sKh, f16* sVh,
                                        int h, int lane, int l15, int g)
{
    const f32x4 z4 = {0.f, 0.f, 0.f, 0.f};
    f32x4 acc[6][2];
    #pragma unroll
    for (int i = 0; i < 6; ++i) { acc[i][0] = z4; acc[i][1] = z4; }
    #pragma unroll
    for (int kt = 0; kt < 6; ++kt) {
        f16x8 x0 = *(const f16x8*)(xh + l15*XS + kt*32 + g*8);
        f16x8 x1 = *(const f16x8*)(xh + (16 + l15)*XS + kt*32 + g*8);
        f16x8 af[6];
        #pragma unroll
        for (int i = 0; i < 6; ++i) {
            if constexpr (W16)
                af[i] = *(const f16x8*)(ws + (((h*6 + kt)*6 + i) << 9) + (lane << 3));
            else {
                int row = (i >> 1)*192 + h*32 + (i & 1)*16 + l15;
                af[i] = ldx8(wf32 + row*192 + kt*32 + g*8);
            }
        }
        #pragma unroll
        for (int i = 0; i < 6; ++i) {
            acc[i][0] = MFMA16(af[i], x0, acc[i][0]);
            acc[i][1] = MFMA16(af[i], x1, acc[i][1]);
        }
    }
    #pragma unroll
    for (int i = 0; i < 6; ++i) {
        int which = i >> 1, sub = i & 1;
        int db  = sub*16 + 4*g;
        f16* region = (which == 0) ? sQh : ((which == 1) ? sKh : sVh);
        #pragma unroll
        for (int nt = 0; nt < 2; ++nt) {
            int token = 16*nt + l15;
            f32x4 a = acc[i][nt];
            if (which == 2) {       // Yv token-major [n][dv] for vectorized conv
                f16x4 o;
                o[0]=(f16)a[0]; o[1]=(f16)a[1]; o[2]=(f16)a[2]; o[3]=(f16)a[3];
                *(f16x4*)(region + token*QS + db) = o;
            } else {                // Yq/Yk channel-major [d][n]
                region[(db+0)*QS + token] = (f16)a[0];
                region[(db+1)*QS + token] = (f16)a[1];
                region[(db+2)*QS + token] = (f16)a[2];
                region[(db+3)*QS + token] = (f16)a[3];
            }
        }
    }
}

template<bool W16>
__global__ __launch_bounds__(768, 3)
void vsa_kernel(const float* __restrict__ x,
                const float* __restrict__ qkv_w, const float* __restrict__ qkv_b,
                const float* __restrict__ proj_w, const float* __restrict__ proj_b,
                const float* __restrict__ rpb_table, const float* __restrict__ temperature,
                const float* __restrict__ qkvC_w, const float* __restrict__ dw_w,
                const float* __restrict__ projC_w, const float* __restrict__ projC_b,
                const float* __restrict__ gs_w1, const float* __restrict__ gs_b1,
                const float* __restrict__ bn_g, const float* __restrict__ bn_b,
                const float* __restrict__ bn_m, const float* __restrict__ bn_v,
                const float* __restrict__ gs_w2, const float* __restrict__ gs_b2,
                const f16* __restrict__ ws, float* __restrict__ out)
{
    // 12 waves = 2 batch elements x (wave == head); 3,3,3,3 SIMD placement.
    // R21: max-free softmax (logits analytically bounded << 88; softmax is
    // shift-invariant) -> halves each softmax's serial shfl reduction depth.
    __shared__ __align__(16) f16 sQKV[2*HALF_TOTAL];
    __shared__ float aspl[32];

    const int t    = threadIdx.x;
    const int w12  = t >> 6;          // 0..11
    const int half = (w12 >= 6);      // batch sub-element
    const int h    = w12 - 6*half;    // wave == head, 0..5
    const int lane = t & 63;
    const int l15  = lane & 15;
    const int g    = lane >> 4;       // 0..3

    const float* xb = x + ((size_t)blockIdx.x*2 + half) * 6144;
    const f32x4 z4 = {0.f, 0.f, 0.f, 0.f};

    f16* base = sQKV + half*HALF_TOTAL;
    f16* sQh = base + h*HSZ;          // q -> P -> Yq -> P_c
    f16* sKh = base + OFFK + h*HSZ;   // k -> Yk -> O2
    f16* sVh = base + OFFV + h*HSZ;   // v^T -> Yv
    f16* sOh = base + OFFO + h*HSZ;   // O (branch-1 out), survives to proj
    f16* xh  = base + XOFF;           // f16 x tile [32][XS]

    // hoisted per-head scalars (long-latency chains overlap later work)
    const float temph = temperature[h];
    const float dlog  = logf(1.0f - exp2f(-2.0f - (2.0f*(float)h)/3.0f));

    // ---- spatial gate (one wave): batch-independent (pooled == 1/32 exactly) ----
    if (t < 32) {
        float y1 = gs_b1[t];
        #pragma unroll
        for (int hh = 0; hh < 6; ++hh) y1 += gs_w1[t*54 + hh*9 + 4] * (1.0f/32.0f);
        y1 = (y1 - bn_m[t]) * rsqrtf(bn_v[t] + 1e-5f) * bn_g[t] + bn_b[t];
        float y2 = gs_b2[t];
        #pragma unroll
        for (int c = 0; c < 32; ++c)
            y2 += gs_w2[t*288 + c*9 + 4] * __shfl(y1, c);
        aspl[t] = 1.0f + y2;
    }

    // ---- stage x as f16 into own half's LDS (coalesced, 2 chunks/thread) ----
    {
        int tl = t - half*384;        // 0..383
        #pragma unroll
        for (int it = 0; it < 2; ++it) {
            int c = tl + 384*it;      // 0..767 chunks of 8 halfs
            int row = c / 24, col = c % 24;
            f16x8 v = ldx8(xb + row*192 + col*8);
            *(f16x8*)(xh + row*XS + col*8) = v;
        }
    }
    __syncthreads();   // b0: x tiles staged

    // ========== GEMM1: this head's q,k,v (single 6-tile group) ==========
    g1_all<W16>(ws + W_QKV, qkv_w, xh, qkv_b, sQh, sKh, sVh, h, lane, l15, g);
    // no barrier: all wave-private

    // ========== branch-1 attention (wave-private) ==========
    {
        f16x8 qa[2], kb[2];
        #pragma unroll
        for (int mt = 0; mt < 2; ++mt)
            qa[mt] = *(const f16x8*)(sQh + (16*mt + l15)*QS + 8*g);
        #pragma unroll
        for (int nt = 0; nt < 2; ++nt)
            kb[nt] = *(const f16x8*)(sKh + (16*nt + l15)*QS + 8*g);
        f32x4 s[2][2];
        #pragma unroll
        for (int mt = 0; mt < 2; ++mt)
            #pragma unroll
            for (int nt = 0; nt < 2; ++nt)
                s[mt][nt] = MFMA16(qa[mt], kb[nt], z4);

        float pr[2][2][4];
        if constexpr (W16) {
            #pragma unroll
            for (int mt = 0; mt < 2; ++mt)
                #pragma unroll
                for (int nt = 0; nt < 2; ++nt) {
                    f16x4 rv = *(const f16x4*)(ws + W_RPB + h*1024
                               + (16*nt + l15)*32 + 16*mt + 4*g);
                    #pragma unroll
                    for (int r = 0; r < 4; ++r)
                        pr[mt][nt][r] = s[mt][nt][r] + (float)rv[r];
                }
        } else {
            #pragma unroll
            for (int mt = 0; mt < 2; ++mt)
                #pragma unroll
                for (int nt = 0; nt < 2; ++nt)
                    #pragma unroll
                    for (int r = 0; r < 4; ++r) {
                        int m = 16*mt + 4*g + r, n = 16*nt + l15;
                        int dh = (m>>3) - (n>>3) + 3;
                        int dwd = (m&7) - (n&7) + 7;
                        pr[mt][nt][r] = s[mt][nt][r] + rpb_table[(dh*15+dwd)*6 + h];
                    }
        }
        // max-free softmax: logits bounded (|s| small), exp cannot overflow
        #pragma unroll
        for (int mt = 0; mt < 2; ++mt)
            #pragma unroll
            for (int r = 0; r < 4; ++r) {
                float e0 = __expf(pr[mt][0][r]);
                float e1 = __expf(pr[mt][1][r]);
                float sm = e0 + e1;
                sm += __shfl_xor(sm, 1);
                sm += __shfl_xor(sm, 2);
                sm += __shfl_xor(sm, 4);
                sm += __shfl_xor(sm, 8);
                float inv = 1.0f / sm;
                pr[mt][0][r] = e0*inv;
                pr[mt][1][r] = e1*inv;
            }
        // P overwrites Q region (qa already in regs; wave-private)
        #pragma unroll
        for (int mt = 0; mt < 2; ++mt)
            #pragma unroll
            for (int nt = 0; nt < 2; ++nt)
                #pragma unroll
                for (int r = 0; r < 4; ++r)
                    sQh[(16*mt + 4*g + r)*QS + 16*nt + l15] = (f16)pr[mt][nt][r];

        // O^T = V^T @ P^T ; O -> O bank [token][d]
        f16x8 va[2], pb[2];
        #pragma unroll
        for (int mt = 0; mt < 2; ++mt)
            va[mt] = *(const f16x8*)(sVh + (16*mt + l15)*QS + 8*g);
        #pragma unroll
        for (int nt = 0; nt < 2; ++nt)
            pb[nt] = *(const f16x8*)(sQh + (16*nt + l15)*QS + 8*g);
        #pragma unroll
        for (int mt = 0; mt < 2; ++mt)
            #pragma unroll
            for (int nt = 0; nt < 2; ++nt) {
                f32x4 o = MFMA16(va[mt], pb[nt], z4);
                int token = 16*nt + l15;
                int dbv = 16*mt + 4*g;
                f16x4 ov;
                ov[0]=(f16)o[0]; ov[1]=(f16)o[1]; ov[2]=(f16)o[2]; ov[3]=(f16)o[3];
                *(f16x4*)(sOh + token*QS + dbv) = ov;
            }
    }

    // ========== GEMM1C: this head's Y (single 6-tile group), wave-private ==========
    g1c_all<W16>(ws + W_QKVC, qkvC_w, xh, sQh, sKh, sVh, h, lane, l15, g);

    // ========== branch-2 (MDTA), wave-private; packed-f16 convolutions ==========
    {
        const f16x8 zz = {0,0,0,0,0,0,0,0};
        f16x8 qa[2], kb[2], vb[2];
        // q/k: depthwise 3x3 via f16x8 vector FMA (+ shifted shuffles) + f32 l2norm
        #pragma unroll
        for (int mt = 0; mt < 2; ++mt) {
            int d = 16*mt + l15;
            #pragma unroll
            for (int qk = 0; qk < 2; ++qk) {
                int ch = qk*192 + h*32 + d;
                f16 wr[9];
                if constexpr (W16) {
                    #pragma unroll
                    for (int i2 = 0; i2 < 9; ++i2)
                        wr[i2] = ws[W_DWT + i2*576 + ch];
                } else {
                    const float* wp = dw_w + ch*9;
                    #pragma unroll
                    for (int i2 = 0; i2 < 9; ++i2) wr[i2] = (f16)wp[i2];
                }
                const f16* yr = (qk ? sKh : sQh) + d*QS;
                f16x8 zv = zz;
                #pragma unroll
                for (int dh2 = 0; dh2 < 3; ++dh2) {
                    int h2 = g + dh2 - 1;
                    if (h2 >= 0 && h2 < 4) {
                        f16x8 rv = *(const f16x8*)(yr + 8*h2);
                        f16x8 sm1 = __builtin_shufflevector(rv, zz, 8,0,1,2,3,4,5,6);
                        f16x8 sp1 = __builtin_shufflevector(rv, zz, 1,2,3,4,5,6,7,8);
                        zv += sm1 * wr[dh2*3+0];
                        zv += rv  * wr[dh2*3+1];
                        zv += sp1 * wr[dh2*3+2];
                    }
                }
                float ss = 0.f;
                #pragma unroll
                for (int b2 = 0; b2 < 8; ++b2) {
                    float zf = (float)zv[b2];
                    ss += zf*zf;
                }
                ss += __shfl_xor(ss, 16);
                ss += __shfl_xor(ss, 32);
                float inv = 1.0f / fmaxf(sqrtf(ss), 1e-12f);
                f16 invh = (f16)inv;
                if (qk == 0) qa[mt] = zv * invh;
                else         kb[mt] = zv * invh;
            }
        }
        // vc: depthwise on token-major Yv; tap-outer, packed f16 accumulate
        {
            f16x8 av0 = zz, av1 = zz;
            #pragma unroll
            for (int dh2 = 0; dh2 < 3; ++dh2)
                #pragma unroll
                for (int dw2 = 0; dw2 < 3; ++dw2) {
                    f16x8 w8;
                    if constexpr (W16) {
                        w8 = *(const f16x8*)(ws + W_DWT + (dh2*3+dw2)*576
                                             + 384 + h*32 + 8*g);
                    } else {
                        #pragma unroll
                        for (int b2 = 0; b2 < 8; ++b2)
                            w8[b2] = (f16)dw_w[(384+h*32+8*g+b2)*9 + dh2*3+dw2];
                    }
                    {   // nt = 0
                        int n = l15;
                        int h2 = (n >> 3) + dh2 - 1;
                        int w2 = (n & 7) + dw2 - 1;
                        if (h2 >= 0 && h2 < 4 && w2 >= 0 && w2 < 8) {
                            f16x8 v8 = *(const f16x8*)(sVh + (h2*8+w2)*QS + 8*g);
                            av0 += w8 * v8;
                        }
                    }
                    {   // nt = 1
                        int n = 16 + l15;
                        int h2 = (n >> 3) + dh2 - 1;
                        int w2 = (n & 7) + dw2 - 1;
                        if (h2 >= 0 && h2 < 4 && w2 >= 0 && w2 < 8) {
                            f16x8 v8 = *(const f16x8*)(sVh + (h2*8+w2)*QS + 8*g);
                            av1 += w8 * v8;
                        }
                    }
                }
            vb[0] = av0; vb[1] = av1;
        }
        // S_c = qc kc^T * temp + |d-d'|*dlog ; max-free softmax (|S_c| <= ~40)
        f32x4 s[2][2];
        #pragma unroll
        for (int mt = 0; mt < 2; ++mt)
            #pragma unroll
            for (int nt = 0; nt < 2; ++nt)
                s[mt][nt] = MFMA16(qa[mt], kb[nt], z4);
        float pr[2][2][4];
        #pragma unroll
        for (int mt = 0; mt < 2; ++mt)
            #pragma unroll
            for (int nt = 0; nt < 2; ++nt)
                #pragma unroll
                for (int r = 0; r < 4; ++r) {
                    int di = 16*mt + 4*g + r, dj = 16*nt + l15;
                    pr[mt][nt][r] = s[mt][nt][r]*temph + fabsf((float)(di - dj))*dlog;
                }
        #pragma unroll
        for (int mt = 0; mt < 2; ++mt)
            #pragma unroll
            for (int r = 0; r < 4; ++r) {
                float e0 = __expf(pr[mt][0][r]);
                float e1 = __expf(pr[mt][1][r]);
                float sm = e0 + e1;
                sm += __shfl_xor(sm, 1);
                sm += __shfl_xor(sm, 2);
                sm += __shfl_xor(sm, 4);
                sm += __shfl_xor(sm, 8);
                float inv = 1.0f / sm;
                pr[mt][0][r] = e0*inv;
                pr[mt][1][r] = e1*inv;
            }
        // P_c overwrites Yq region (consumed into qa; wave-private)
        #pragma unroll
        for (int mt = 0; mt < 2; ++mt)
            #pragma unroll
            for (int nt = 0; nt < 2; ++nt)
                #pragma unroll
                for (int r = 0; r < 4; ++r)
                    sQh[(16*mt + 4*g + r)*QS + 16*nt + l15] = (f16)pr[mt][nt][r];
        // x2pre[d][n] = P_c @ vc -> O2 into K region (Yk consumed into kb above)
        f16x8 pa[2];
        #pragma unroll
        for (int mt = 0; mt < 2; ++mt)
            pa[mt] = *(const f16x8*)(sQh + (16*mt + l15)*QS + 8*g);
        #pragma unroll
        for (int mt = 0; mt < 2; ++mt)
            #pragma unroll
            for (int nt = 0; nt < 2; ++nt) {
                f32x4 o = MFMA16(pa[mt], vb[nt], z4);
                int token = 16*nt + l15;
                int dbv = 16*mt + 4*g;
                f16x4 ov;
                ov[0]=(f16)o[0]; ov[1]=(f16)o[1]; ov[2]=(f16)o[2]; ov[3]=(f16)o[3];
                *(f16x4*)(sKh + token*QS + dbv) = ov;
            }
    }
    __syncthreads();   // b1: O (O banks) and O2 (K regions) ready across all heads

    // ========== deferred proj + projC (wave h -> cols 32h..32h+31, own half) =======
    f32x4 acc1[2][2], acc2[2][2];
    {
        #pragma unroll
        for (int ct = 0; ct < 2; ++ct) {
            float b1f = proj_b[32*h + 16*ct + l15];
            float b2f = projC_b[32*h + 16*ct + l15];
            f32x4 v1 = {b1f, b1f, b1f, b1f};
            f32x4 v2 = {b2f, b2f, b2f, b2f};
            acc1[0][ct] = v1; acc1[1][ct] = v1;
            acc2[0][ct] = v2; acc2[1][ct] = v2;
        }
        #pragma unroll
        for (int kt = 0; kt < 6; ++kt) {     // K-chunk kt == head kt
            f16x8 aa1[2], aa2[2], bb1[2], bb2[2];
            #pragma unroll
            for (int mt = 0; mt < 2; ++mt) {
                aa1[mt] = *(const f16x8*)(base + OFFO + kt*HSZ + (16*mt + l15)*QS + 8*g);
                aa2[mt] = *(const f16x8*)(base + OFFK + kt*HSZ + (16*mt + l15)*QS + 8*g);
            }
            #pragma unroll
            for (int ct = 0; ct < 2; ++ct) {
                if constexpr (W16) {
                    bb1[ct] = *(const f16x8*)(ws + W_PROJ
                              + (((h*6 + kt)*2 + ct) << 9) + (lane << 3));
                    bb2[ct] = *(const f16x8*)(ws + W_PROJC
                              + (((h*6 + kt)*2 + ct) << 9) + (lane << 3));
                } else {
                    bb1[ct] = ldx8(proj_w  + (32*h + 16*ct + l15)*192 + kt*32 + 8*g);
                    bb2[ct] = ldx8(projC_w + (32*h + 16*ct + l15)*192 + kt*32 + 8*g);
                }
            }
            #pragma unroll
            for (int mt = 0; mt < 2; ++mt)
                #pragma unroll
                for (int ct = 0; ct < 2; ++ct) {
                    acc1[mt][ct] = MFMA16(aa1[mt], bb1[ct], acc1[mt][ct]);
                    acc2[mt][ct] = MFMA16(aa2[mt], bb2[ct], acc2[mt][ct]);
                }
        }
    }
    __syncthreads();   // b2: all O/O2 reads done -> pool reusable as fp32 sOut

    // ========== epilogue: stage fp32 result in own LDS half, coalesced store =========
    float* sOut = (float*)base;
    #pragma unroll
    for (int mt = 0; mt < 2; ++mt)
        #pragma unroll
        for (int r = 0; r < 4; ++r) {
            int m = 16*mt + 4*g + r;
            float asp = aspl[m];
            #pragma unroll
            for (int ct = 0; ct < 2; ++ct) {
                int c = 32*h + 16*ct + l15;
                sOut[m*192 + c] = acc1[mt][ct][r] + acc2[mt][ct][r]*asp;
            }
        }
    __syncthreads();   // b3
    {
        int tl = t - half*384;   // 0..383 within half
        const float4* sOv = (const float4*)sOut;
        float4* ob4 = (float4*)(out + ((size_t)blockIdx.x*2 + half) * 6144);
        #pragma unroll
        for (int it = 0; it < 4; ++it)
            ob4[tl + 384*it] = sOv[tl + 384*it];
    }
}

extern "C" void kernel_launch(void* const* d_in, const int* in_sizes, int n_in,
                              void* d_out, int out_size, void* d_ws, size_t ws_size,
                              hipStream_t stream) {
    (void)n_in; (void)out_size;
    const float* x         = (const float*)d_in[0];
    const float* qkv_w     = (const float*)d_in[1];
    const float* qkv_b     = (const float*)d_in[2];
    const float* proj_w    = (const float*)d_in[3];
    const float* proj_b    = (const float*)d_in[4];
    const float* rpb_table = (const float*)d_in[5];
    const float* temp      = (const float*)d_in[6];
    const float* qkvC_w    = (const float*)d_in[7];
    const float* dw_w      = (const float*)d_in[8];
    const float* projC_w   = (const float*)d_in[9];
    const float* projC_b   = (const float*)d_in[10];
    const float* gs_w1     = (const float*)d_in[11];
    const float* gs_b1     = (const float*)d_in[12];
    const float* bn_g      = (const float*)d_in[13];
    const float* bn_b      = (const float*)d_in[14];
    const float* bn_m      = (const float*)d_in[15];
    const float* bn_v      = (const float*)d_in[16];
    const float* gs_w2     = (const float*)d_in[17];
    const float* gs_b2     = (const float*)d_in[18];
    float* out = (float*)d_out;

    int B = in_sizes[0] / (32 * 192);   // 4096
    bool use_ws = (d_ws != nullptr) && (ws_size >= (size_t)W_TOTAL * sizeof(f16));
    if (use_ws) {
        cvt_weights<<<78, 256, 0, stream>>>(qkv_w, qkvC_w, proj_w, projC_w, dw_w,
                                            rpb_table, (f16*)d_ws);
        vsa_kernel<true><<<B/2, 768, 0, stream>>>(x, qkv_w, qkv_b, proj_w, proj_b,
                                                  rpb_table, temp, qkvC_w, dw_w,
                                                  projC_w, projC_b, gs_w1, gs_b1,
                                                  bn_g, bn_b, bn_m, bn_v, gs_w2, gs_b2,
                                                  (const f16*)d_ws, out);
    } else {
        vsa_kernel<false><<<B/2, 768, 0, stream>>>(x, qkv_w, qkv_b, proj_w, proj_b,
                                                   rpb_table, temp, qkvC_w, dw_w,
                                                   projC_w, projC_b, gs_w1, gs_b1,
                                                   bn_g, bn_b, bn_m, bn_v, gs_w2, gs_b2,
                                                   nullptr, out);
    }
}